// Round 1
// baseline (2865.680 us; speedup 1.0000x reference)
//
#include <hip/hip_runtime.h>
#include <math.h>

#define LQ_ 5440
#define NB_ 8
#define NQ_ (NB_ * LQ_)   // 43520
#define D_  256
#define NH_ 8
#define HD_ 32

// ---------------------------------------------------------------------------
// Generic small-GEMM: C[M,COLS] = (A [+ A2]) @ W + bias, optional ReLU.
// Block = min(COLS,256) threads, 16 rows of A per block, grid.y tiles columns.
// A rows are contiguous, so the 16-row span is one contiguous float4 copy.
// ---------------------------------------------------------------------------
__global__ void gemm16(const float* __restrict__ A, const float* __restrict__ A2,
                       const float* __restrict__ W, const float* __restrict__ bias,
                       float* __restrict__ C, int K, int COLS, int relu) {
    extern __shared__ float As[];               // 16*K floats
    const int t  = threadIdx.x;
    const int r0 = blockIdx.x * 16;
    const float* Ab  = A  + (size_t)r0 * K;
    const float* A2b = A2 ? A2 + (size_t)r0 * K : nullptr;
    const int tot = 16 * K;
    for (int i = 4 * t; i < tot; i += 4 * blockDim.x) {
        float4 v = *(const float4*)(Ab + i);
        if (A2b) {
            float4 u = *(const float4*)(A2b + i);
            v.x += u.x; v.y += u.y; v.z += u.z; v.w += u.w;
        }
        *(float4*)(As + i) = v;
    }
    __syncthreads();

    const int col = blockIdx.y * blockDim.x + t;
    float acc[16];
    #pragma unroll
    for (int r = 0; r < 16; ++r) acc[r] = 0.f;

    #pragma unroll 2
    for (int k = 0; k < K; k += 4) {
        const float w0 = W[(size_t)(k + 0) * COLS + col];
        const float w1 = W[(size_t)(k + 1) * COLS + col];
        const float w2 = W[(size_t)(k + 2) * COLS + col];
        const float w3 = W[(size_t)(k + 3) * COLS + col];
        #pragma unroll
        for (int r = 0; r < 16; ++r) {
            const float4 a = *(const float4*)(As + r * K + k);
            acc[r] += a.x * w0 + a.y * w1 + a.z * w2 + a.w * w3;
        }
    }

    const float b = bias ? bias[col] : 0.f;
    #pragma unroll
    for (int r = 0; r < 16; ++r) {
        float v = acc[r] + b;
        if (relu) v = fmaxf(v, 0.f);
        C[(size_t)(r0 + r) * COLS + col] = v;
    }
}

// ---------------------------------------------------------------------------
// Softmax over contiguous groups of 16 (one thread per group).
// ---------------------------------------------------------------------------
__global__ void softmax16(float* __restrict__ a, int ngroups) {
    const int g = blockIdx.x * blockDim.x + threadIdx.x;
    if (g >= ngroups) return;
    float* p = a + (size_t)g * 16;
    float m = -1e30f;
    #pragma unroll
    for (int i = 0; i < 16; ++i) m = fmaxf(m, p[i]);
    float e[16];
    float s = 0.f;
    #pragma unroll
    for (int i = 0; i < 16; ++i) { e[i] = __expf(p[i] - m); s += e[i]; }
    const float inv = 1.f / s;
    #pragma unroll
    for (int i = 0; i < 16; ++i) p[i] = e[i] * inv;
}

// ---------------------------------------------------------------------------
// Deformable bilinear sampling + attention-weighted sum.
// Block per (n,q); thread t = (h = t>>5, d = t&31).
// value: (N, Lq, NH, HD); off: (N,Lq,NH,NL,NP,2); attn: (N,Lq,NH,16);
// refp: (N,Lq,NL,2); out: (N,Lq,NH,HD).
// ---------------------------------------------------------------------------
__global__ void msda_sample(const float* __restrict__ value, const float* __restrict__ off,
                            const float* __restrict__ attnw, const float* __restrict__ refp,
                            float* __restrict__ out) {
    const int nq = blockIdx.x;
    const int n  = nq / LQ_;
    const int t  = threadIdx.x;
    const int h  = t >> 5;
    const int d  = t & 31;

    const int starts[4] = {0, 4096, 5120, 5376};
    const int dims[4]   = {64, 32, 16, 8};

    const float* ref  = refp  + (size_t)nq * 4 * 2;
    const float* offr = off   + (size_t)nq * 256 + h * 32;   // (l,p,2) for this head
    const float* attr = attnw + (size_t)nq * 128 + h * 16;

    float acc = 0.f;
    #pragma unroll
    for (int l = 0; l < 4; ++l) {
        const int   Wl = dims[l];
        const int   Hl = dims[l];
        const float rx = ref[l * 2 + 0];
        const float ry = ref[l * 2 + 1];
        const float* vbase = value + (((size_t)n * LQ_ + starts[l]) * NH_ + h) * HD_ + d;
        #pragma unroll
        for (int p = 0; p < 4; ++p) {
            const int   oi = (l * 4 + p) * 2;
            const float w  = attr[l * 4 + p];
            const float lx = rx + offr[oi + 0] / (float)Wl;   // norm = (W,H)
            const float ly = ry + offr[oi + 1] / (float)Hl;
            const float x  = lx * (float)Wl - 0.5f;
            const float y  = ly * (float)Hl - 0.5f;
            const float x0f = floorf(x), y0f = floorf(y);
            const int   x0 = (int)x0f, y0 = (int)y0f;
            const float wx1 = x - x0f, wy1 = y - y0f;
            const float wx0 = 1.f - wx1, wy0 = 1.f - wy1;

            const bool xv0 = (x0 >= 0) && (x0 < Wl);
            const bool xv1 = (x0 + 1 >= 0) && (x0 + 1 < Wl);
            const bool yv0 = (y0 >= 0) && (y0 < Hl);
            const bool yv1 = (y0 + 1 >= 0) && (y0 + 1 < Hl);

            float v00 = 0.f, v01 = 0.f, v10 = 0.f, v11 = 0.f;
            if (yv0) {
                const float* vr = vbase + (size_t)y0 * Wl * 256;
                if (xv0) v00 = vr[(size_t)x0 * 256];
                if (xv1) v01 = vr[(size_t)(x0 + 1) * 256];
            }
            if (yv1) {
                const float* vr = vbase + (size_t)(y0 + 1) * Wl * 256;
                if (xv0) v10 = vr[(size_t)x0 * 256];
                if (xv1) v11 = vr[(size_t)(x0 + 1) * 256];
            }
            acc += w * (wy0 * (wx0 * v00 + wx1 * v01) + wy1 * (wx0 * v10 + wx1 * v11));
        }
    }
    out[(size_t)nq * 256 + t] = acc;
}

// ---------------------------------------------------------------------------
// out = LayerNorm(a + b) * g + beta ; one block (256 thr) per row of 256.
// ---------------------------------------------------------------------------
__global__ void add_ln(const float* __restrict__ a, const float* __restrict__ b,
                       const float* __restrict__ g, const float* __restrict__ be,
                       float* __restrict__ out) {
    const int row = blockIdx.x;
    const int t   = threadIdx.x;
    const size_t idx = (size_t)row * 256 + t;
    const float x = a[idx] + b[idx];

    __shared__ float sm[4];
    float v = x;
    #pragma unroll
    for (int o = 32; o > 0; o >>= 1) v += __shfl_down(v, o);
    if ((t & 63) == 0) sm[t >> 6] = v;
    __syncthreads();
    const float mu = (sm[0] + sm[1] + sm[2] + sm[3]) * (1.f / 256.f);
    __syncthreads();

    const float dx = x - mu;
    v = dx * dx;
    #pragma unroll
    for (int o = 32; o > 0; o >>= 1) v += __shfl_down(v, o);
    if ((t & 63) == 0) sm[t >> 6] = v;
    __syncthreads();
    const float var = (sm[0] + sm[1] + sm[2] + sm[3]) * (1.f / 256.f);

    out[idx] = dx * rsqrtf(var + 1e-5f) * g[t] + be[t];
}

// ---------------------------------------------------------------------------
extern "C" void kernel_launch(void* const* d_in, const int* in_sizes, int n_in,
                              void* d_out, int out_size, void* d_ws, size_t ws_size,
                              hipStream_t stream) {
    const float* src     = (const float*)d_in[0];
    const float* pos     = (const float*)d_in[1];
    const float* refp    = (const float*)d_in[2];
    // d_in[3] = spatial_shapes (static, hardcoded)
    const float* W_value = (const float*)d_in[4];
    const float* b_value = (const float*)d_in[5];
    const float* W_off   = (const float*)d_in[6];
    const float* b_off   = (const float*)d_in[7];
    const float* W_attn  = (const float*)d_in[8];
    const float* b_attn  = (const float*)d_in[9];
    const float* W_out   = (const float*)d_in[10];
    const float* b_out   = (const float*)d_in[11];
    const float* ln1g    = (const float*)d_in[12];
    const float* ln1b    = (const float*)d_in[13];
    const float* W1      = (const float*)d_in[14];
    const float* b1      = (const float*)d_in[15];
    const float* W2      = (const float*)d_in[16];
    const float* b2      = (const float*)d_in[17];
    const float* ln2g    = (const float*)d_in[18];
    const float* ln2b    = (const float*)d_in[19];
    float* out = (float*)d_out;
    float* ws  = (float*)d_ws;

    // workspace layout (floats); overlays chosen so lifetimes never collide:
    //   F : [0,        11141120)  src2, later ffn2
    //   G : [11141120, 22282240)  value, later x
    //   R : [22282240, 66846720)  off | attn | sampled, later ffn hidden (1024/row)
    float* F  = ws;
    float* G  = ws + 11141120;
    float* R  = ws + 22282240;
    float* C  = R;               // off     (11141120 floats)
    float* Dd = R + 11141120;    // attn    ( 5570560 floats)
    float* E  = R + 16711680;    // sampled (11141120 floats)
    float* Hh = R;               // ffn hidden (44564480 floats)

    const int nblk = NQ_ / 16;   // 2720

    // 1. value = src @ W_value + b_value            -> G
    gemm16<<<dim3(nblk, 1), 256, 16 * 256 * 4, stream>>>(src, nullptr, W_value, b_value, G, 256, 256, 0);
    // 2. off = (src+pos) @ W_off + b_off            -> C
    gemm16<<<dim3(nblk, 1), 256, 16 * 256 * 4, stream>>>(src, pos, W_off, b_off, C, 256, 256, 0);
    // 3. attn logits = (src+pos) @ W_attn + b_attn  -> Dd
    gemm16<<<dim3(nblk, 1), 128, 16 * 256 * 4, stream>>>(src, pos, W_attn, b_attn, Dd, 256, 128, 0);
    // 4. softmax over 16 per (n,q,h), in place
    softmax16<<<dim3((NQ_ * 8 + 255) / 256), 256, 0, stream>>>(Dd, NQ_ * 8);
    // 5. deformable sampling                        -> E
    msda_sample<<<dim3(NQ_), 256, 0, stream>>>(G, C, Dd, refp, E);
    // 6. src2 = E @ W_out + b_out                   -> F
    gemm16<<<dim3(nblk, 1), 256, 16 * 256 * 4, stream>>>(E, nullptr, W_out, b_out, F, 256, 256, 0);
    // 7. x = LN(src + src2)                         -> G
    add_ln<<<dim3(NQ_), 256, 0, stream>>>(src, F, ln1g, ln1b, G);
    // 8. h = relu(x @ W1 + b1)                      -> Hh (COLS=1024, grid.y=4)
    gemm16<<<dim3(nblk, 4), 256, 16 * 256 * 4, stream>>>(G, nullptr, W1, b1, Hh, 256, 1024, 1);
    // 9. ffn2 = h @ W2 + b2                         -> F (K=1024, 64 KiB LDS)
    gemm16<<<dim3(nblk, 1), 256, 16 * 1024 * 4, stream>>>(Hh, nullptr, W2, b2, F, 1024, 256, 0);
    // 10. out = LN(x + ffn2)                        -> d_out
    add_ln<<<dim3(NQ_), 256, 0, stream>>>(G, F, ln2g, ln2b, out);
}

// Round 2
// 1197.832 us; speedup vs baseline: 2.3924x; 2.3924x over previous
//
#include <hip/hip_runtime.h>
#include <math.h>

#define LQ_ 5440
#define NB_ 8
#define NQ_ (NB_ * LQ_)   // 43520
#define D_  256
#define NH_ 8
#define HD_ 32

typedef __attribute__((ext_vector_type(8))) short short8;
typedef __attribute__((ext_vector_type(4))) float f32x4;

__device__ __forceinline__ ushort f2bf(float f) {
    union { float f; unsigned u; } v; v.f = f;
    unsigned u = v.u;
    unsigned r = (u + 0x7FFFu + ((u >> 16) & 1u)) >> 16;
    return (ushort)r;
}
__device__ __forceinline__ float bf2f(ushort u) {
    union { unsigned u; float f; } v; v.u = ((unsigned)u) << 16; return v.f;
}

// ---------------------------------------------------------------------------
// Input prep: s_bf = bf16(src), q_bf = bf16(src+pos). 4 elems/thread.
// ---------------------------------------------------------------------------
__global__ void make_bf_inputs(const float* __restrict__ src, const float* __restrict__ pos,
                               ushort* __restrict__ s_bf, ushort* __restrict__ q_bf) {
    const int i = blockIdx.x * blockDim.x + threadIdx.x;
    const float4 s = ((const float4*)src)[i];
    const float4 p = ((const float4*)pos)[i];
    ushort4 a, b;
    a.x = f2bf(s.x); a.y = f2bf(s.y); a.z = f2bf(s.z); a.w = f2bf(s.w);
    b.x = f2bf(s.x + p.x); b.y = f2bf(s.y + p.y); b.z = f2bf(s.z + p.z); b.w = f2bf(s.w + p.w);
    ((ushort4*)s_bf)[i] = a;
    ((ushort4*)q_bf)[i] = b;
}

// ---------------------------------------------------------------------------
// Weight transpose + bf16 cast: W [K,N] fp32 -> Wt [N,K] bf16.
// ---------------------------------------------------------------------------
__global__ void transpose_w(const float* __restrict__ W, ushort* __restrict__ Wt, int K, int N) {
    __shared__ float tile[32][33];
    const int bx = blockIdx.x;   // n tile
    const int by = blockIdx.y;   // k tile
    const int tx = threadIdx.x;  // 0..31
    const int ty = threadIdx.y;  // 0..7
    for (int i = ty; i < 32; i += 8)
        tile[i][tx] = W[(size_t)(by * 32 + i) * N + bx * 32 + tx];
    __syncthreads();
    for (int i = ty; i < 32; i += 8)
        Wt[(size_t)(bx * 32 + i) * K + by * 32 + tx] = f2bf(tile[tx][i]);
}

// ---------------------------------------------------------------------------
// MFMA GEMM: C[M,N] = A[M,K](bf16) @ Bt[N,K](bf16)^T + bias, opt ReLU.
// 128x128 tile, BK=64, 4 waves, 4x4 16x16x32 tiles/wave. fp32 or bf16 out.
// ---------------------------------------------------------------------------
#define BM 128
#define BN 128
#define BKE 64
#define LDE 72   // padded LDS row (elems): 144 B -> 2-way banked (free)

__global__ __launch_bounds__(256)
void mfma_gemm(const ushort* __restrict__ A, const ushort* __restrict__ Bt,
               const float* __restrict__ bias, float* __restrict__ Cf,
               ushort* __restrict__ Cb, int N, int K, int relu) {
    __shared__ ushort lA[BM * LDE];
    __shared__ ushort lB[BN * LDE];
    const int t    = threadIdx.x;
    const int row0 = blockIdx.x * BM;
    const int col0 = blockIdx.y * BN;
    const int w    = t >> 6;
    const int lane = t & 63;
    const int lr   = lane & 15;
    const int quad = lane >> 4;
    const int wm   = (w >> 1) * 64;
    const int wn   = (w & 1) * 64;

    f32x4 acc[4][4];
    #pragma unroll
    for (int i = 0; i < 4; ++i)
        #pragma unroll
        for (int j = 0; j < 4; ++j)
            acc[i][j] = (f32x4){0.f, 0.f, 0.f, 0.f};

    const int sr = t >> 3;        // 0..31
    const int sc = (t & 7) * 8;   // elem offset in row

    for (int k0 = 0; k0 < K; k0 += BKE) {
        __syncthreads();
        #pragma unroll
        for (int g = 0; g < 4; ++g) {
            const int r = sr + g * 32;
            *(short8*)(lA + r * LDE + sc) = *(const short8*)(A  + (size_t)(row0 + r) * K + k0 + sc);
            *(short8*)(lB + r * LDE + sc) = *(const short8*)(Bt + (size_t)(col0 + r) * K + k0 + sc);
        }
        __syncthreads();
        #pragma unroll
        for (int kk = 0; kk < 2; ++kk) {
            short8 af[4], bfr[4];
            #pragma unroll
            for (int i = 0; i < 4; ++i)
                af[i] = *(const short8*)(lA + (wm + i * 16 + lr) * LDE + kk * 32 + quad * 8);
            #pragma unroll
            for (int j = 0; j < 4; ++j)
                bfr[j] = *(const short8*)(lB + (wn + j * 16 + lr) * LDE + kk * 32 + quad * 8);
            #pragma unroll
            for (int i = 0; i < 4; ++i)
                #pragma unroll
                for (int j = 0; j < 4; ++j)
                    acc[i][j] = __builtin_amdgcn_mfma_f32_16x16x32_bf16(af[i], bfr[j], acc[i][j], 0, 0, 0);
        }
    }

    #pragma unroll
    for (int j = 0; j < 4; ++j) {
        const int col = col0 + wn + j * 16 + lr;
        const float bb = bias ? bias[col] : 0.f;
        #pragma unroll
        for (int i = 0; i < 4; ++i) {
            const int rbase = row0 + wm + i * 16 + quad * 4;
            #pragma unroll
            for (int r = 0; r < 4; ++r) {
                float v = acc[i][j][r] + bb;
                if (relu) v = fmaxf(v, 0.f);
                if (Cf) Cf[(size_t)(rbase + r) * N + col] = v;
                else    Cb[(size_t)(rbase + r) * N + col] = f2bf(v);
            }
        }
    }
}

// ---------------------------------------------------------------------------
// Softmax over contiguous groups of 16 (one thread per group), fp32 in place.
// ---------------------------------------------------------------------------
__global__ void softmax16(float* __restrict__ a, int ngroups) {
    const int g = blockIdx.x * blockDim.x + threadIdx.x;
    if (g >= ngroups) return;
    float* p = a + (size_t)g * 16;
    float m = -1e30f;
    #pragma unroll
    for (int i = 0; i < 16; ++i) m = fmaxf(m, p[i]);
    float e[16];
    float s = 0.f;
    #pragma unroll
    for (int i = 0; i < 16; ++i) { e[i] = __expf(p[i] - m); s += e[i]; }
    const float inv = 1.f / s;
    #pragma unroll
    for (int i = 0; i < 16; ++i) p[i] = e[i] * inv;
}

// ---------------------------------------------------------------------------
// Deformable bilinear sampling; value bf16, weights fp32, out bf16.
// Block per (n,q); thread t = (h = t>>5, d = t&31).
// ---------------------------------------------------------------------------
__global__ void msda_sample(const ushort* __restrict__ value, const float* __restrict__ off,
                            const float* __restrict__ attnw, const float* __restrict__ refp,
                            ushort* __restrict__ out) {
    const int nq = blockIdx.x;
    const int n  = nq / LQ_;
    const int t  = threadIdx.x;
    const int h  = t >> 5;
    const int d  = t & 31;

    const int starts[4] = {0, 4096, 5120, 5376};
    const int dims[4]   = {64, 32, 16, 8};

    const float* ref  = refp  + (size_t)nq * 8;
    const float* offr = off   + (size_t)nq * 256 + h * 32;
    const float* attr = attnw + (size_t)nq * 128 + h * 16;

    float acc = 0.f;
    #pragma unroll
    for (int l = 0; l < 4; ++l) {
        const int   Wl = dims[l];
        const int   Hl = dims[l];
        const float rx = ref[l * 2 + 0];
        const float ry = ref[l * 2 + 1];
        const ushort* vbase = value + (((size_t)n * LQ_ + starts[l]) * NH_ + h) * HD_ + d;
        #pragma unroll
        for (int p = 0; p < 4; ++p) {
            const int   oi = (l * 4 + p) * 2;
            const float wgt = attr[l * 4 + p];
            const float lx = rx + offr[oi + 0] / (float)Wl;
            const float ly = ry + offr[oi + 1] / (float)Hl;
            const float x  = lx * (float)Wl - 0.5f;
            const float y  = ly * (float)Hl - 0.5f;
            const float x0f = floorf(x), y0f = floorf(y);
            const int   x0 = (int)x0f, y0 = (int)y0f;
            const float wx1 = x - x0f, wy1 = y - y0f;
            const float wx0 = 1.f - wx1, wy0 = 1.f - wy1;

            const bool xv0 = (x0 >= 0) && (x0 < Wl);
            const bool xv1 = (x0 + 1 >= 0) && (x0 + 1 < Wl);
            const bool yv0 = (y0 >= 0) && (y0 < Hl);
            const bool yv1 = (y0 + 1 >= 0) && (y0 + 1 < Hl);

            float v00 = 0.f, v01 = 0.f, v10 = 0.f, v11 = 0.f;
            if (yv0) {
                const ushort* vr = vbase + (size_t)y0 * Wl * 256;
                if (xv0) v00 = bf2f(vr[(size_t)x0 * 256]);
                if (xv1) v01 = bf2f(vr[(size_t)(x0 + 1) * 256]);
            }
            if (yv1) {
                const ushort* vr = vbase + (size_t)(y0 + 1) * Wl * 256;
                if (xv0) v10 = bf2f(vr[(size_t)x0 * 256]);
                if (xv1) v11 = bf2f(vr[(size_t)(x0 + 1) * 256]);
            }
            acc += wgt * (wy0 * (wx0 * v00 + wx1 * v01) + wy1 * (wx0 * v10 + wx1 * v11));
        }
    }
    out[(size_t)nq * 256 + t] = f2bf(acc);
}

// ---------------------------------------------------------------------------
// x = LayerNorm(a + b); writes fp32 x and optionally bf16 x.
// ---------------------------------------------------------------------------
__global__ void add_ln(const float* __restrict__ a, const float* __restrict__ b,
                       const float* __restrict__ g, const float* __restrict__ be,
                       float* __restrict__ xf, ushort* __restrict__ xb) {
    const int row = blockIdx.x;
    const int t   = threadIdx.x;
    const size_t idx = (size_t)row * 256 + t;
    const float x = a[idx] + b[idx];

    __shared__ float sm[4];
    float v = x;
    #pragma unroll
    for (int o = 32; o > 0; o >>= 1) v += __shfl_down(v, o);
    if ((t & 63) == 0) sm[t >> 6] = v;
    __syncthreads();
    const float mu = (sm[0] + sm[1] + sm[2] + sm[3]) * (1.f / 256.f);
    __syncthreads();

    const float dx = x - mu;
    v = dx * dx;
    #pragma unroll
    for (int o = 32; o > 0; o >>= 1) v += __shfl_down(v, o);
    if ((t & 63) == 0) sm[t >> 6] = v;
    __syncthreads();
    const float var = (sm[0] + sm[1] + sm[2] + sm[3]) * (1.f / 256.f);

    const float y = dx * rsqrtf(var + 1e-5f) * g[t] + be[t];
    xf[idx] = y;
    if (xb) xb[idx] = f2bf(y);
}

// ---------------------------------------------------------------------------
extern "C" void kernel_launch(void* const* d_in, const int* in_sizes, int n_in,
                              void* d_out, int out_size, void* d_ws, size_t ws_size,
                              hipStream_t stream) {
    const float* src     = (const float*)d_in[0];
    const float* pos     = (const float*)d_in[1];
    const float* refp    = (const float*)d_in[2];
    const float* W_value = (const float*)d_in[4];
    const float* b_value = (const float*)d_in[5];
    const float* W_off   = (const float*)d_in[6];
    const float* b_off   = (const float*)d_in[7];
    const float* W_attn  = (const float*)d_in[8];
    const float* b_attn  = (const float*)d_in[9];
    const float* W_out   = (const float*)d_in[10];
    const float* b_out   = (const float*)d_in[11];
    const float* ln1g    = (const float*)d_in[12];
    const float* ln1b    = (const float*)d_in[13];
    const float* W1      = (const float*)d_in[14];
    const float* b1      = (const float*)d_in[15];
    const float* W2      = (const float*)d_in[16];
    const float* b2      = (const float*)d_in[17];
    const float* ln2g    = (const float*)d_in[18];
    const float* ln2b    = (const float*)d_in[19];
    float* out = (float*)d_out;
    char*  ws  = (char*)d_ws;

    // ---- workspace layout (byte offsets) ----
    const size_t SZ_BF = (size_t)NQ_ * 256 * 2;   // 22,282,240
    const size_t SZ_F  = (size_t)NQ_ * 256 * 4;   // 44,564,480
    ushort* s_bf    = (ushort*)(ws);                            // [0, 22.28M)
    ushort* q_bf    = (ushort*)(ws + SZ_BF);                    // [22.28M, 44.56M)
    ushort* val_bf  = (ushort*)(ws + 2 * SZ_BF);                // [44.56M, 66.85M)
    float*  offb    = (float*) (ws + 3 * SZ_BF);                // [66.85M, 111.41M)
    float*  attnb   = (float*) (ws + 3 * SZ_BF + SZ_F);         // [111.41M, 133.69M)
    ushort* samp_bf = (ushort*)(ws + 4 * SZ_BF + SZ_F);         // [133.69M, 155.98M)
    ushort* h_bf    = (ushort*)(ws);                            // overlays [0, 89.13M) — s/q/val/off all dead
    ushort* x_bf    = (ushort*)(ws + 3 * SZ_BF + SZ_F);         // overlays attn slot (dead after sampling)
    char*   wbase   = ws + 5 * SZ_BF + SZ_F;                    // 155.98M
    ushort* Wv_t    = (ushort*)(wbase);                         //  65536 el
    ushort* Woff_t  = (ushort*)(wbase + 131072);
    ushort* Wattn_t = (ushort*)(wbase + 262144);                //  32768 el
    ushort* Wout_t  = (ushort*)(wbase + 327680);
    ushort* W1_t    = (ushort*)(wbase + 458752);                // 262144 el
    ushort* W2_t    = (ushort*)(wbase + 983040);                // 262144 el
    char*   fbase   = wbase + 1507328;
    float*  src2    = (float*)(fbase);                          // also ffn2
    float*  xf      = (float*)(fbase + SZ_F);
    // total: 157.48M + 89.13M = ~246.6 MB < ws_size

    // 0. bf16 inputs
    make_bf_inputs<<<dim3((NQ_ * 256 / 4) / 256), 256, 0, stream>>>(src, pos, s_bf, q_bf);
    // 0b. weight transposes (fp32 [K,N] -> bf16 [N,K])
    transpose_w<<<dim3(8, 8),  dim3(32, 8), 0, stream>>>(W_value, Wv_t,   256, 256);
    transpose_w<<<dim3(8, 8),  dim3(32, 8), 0, stream>>>(W_off,   Woff_t, 256, 256);
    transpose_w<<<dim3(4, 8),  dim3(32, 8), 0, stream>>>(W_attn,  Wattn_t,256, 128);
    transpose_w<<<dim3(8, 8),  dim3(32, 8), 0, stream>>>(W_out,   Wout_t, 256, 256);
    transpose_w<<<dim3(32, 8), dim3(32, 8), 0, stream>>>(W1,      W1_t,   256, 1024);
    transpose_w<<<dim3(8, 32), dim3(32, 8), 0, stream>>>(W2,      W2_t,   1024, 256);

    const int MT = NQ_ / BM;  // 340

    // 1. value = src @ Wv + bv  (bf16 out)
    mfma_gemm<<<dim3(MT, 2), 256, 0, stream>>>(s_bf, Wv_t, b_value, nullptr, val_bf, 256, 256, 0);
    // 2. off = q @ Woff + boff  (fp32 out)
    mfma_gemm<<<dim3(MT, 2), 256, 0, stream>>>(q_bf, Woff_t, b_off, offb, nullptr, 256, 256, 0);
    // 3. attn logits = q @ Wattn + battn (fp32 out)
    mfma_gemm<<<dim3(MT, 1), 256, 0, stream>>>(q_bf, Wattn_t, b_attn, attnb, nullptr, 128, 256, 0);
    // 4. softmax over 16
    softmax16<<<dim3((NQ_ * 8 + 255) / 256), 256, 0, stream>>>(attnb, NQ_ * 8);
    // 5. sampling -> bf16
    msda_sample<<<dim3(NQ_), 256, 0, stream>>>(val_bf, offb, attnb, refp, samp_bf);
    // 6. src2 = sampled @ Wout + bout (fp32)
    mfma_gemm<<<dim3(MT, 2), 256, 0, stream>>>(samp_bf, Wout_t, b_out, src2, nullptr, 256, 256, 0);
    // 7. x = LN(src + src2) -> fp32 + bf16
    add_ln<<<dim3(NQ_), 256, 0, stream>>>(src, src2, ln1g, ln1b, xf, x_bf);
    // 8. h = relu(x @ W1 + b1) -> bf16
    mfma_gemm<<<dim3(MT, 8), 256, 0, stream>>>(x_bf, W1_t, b1, nullptr, h_bf, 1024, 256, 1);
    // 9. ffn2 = h @ W2 + b2 -> fp32 (overlays src2)
    mfma_gemm<<<dim3(MT, 2), 256, 0, stream>>>(h_bf, W2_t, b2, src2, nullptr, 256, 1024, 0);
    // 10. out = LN(x + ffn2)
    add_ln<<<dim3(NQ_), 256, 0, stream>>>(xf, src2, ln2g, ln2b, out, nullptr);
}

// Round 3
// 559.338 us; speedup vs baseline: 5.1233x; 2.1415x over previous
//
#include <hip/hip_runtime.h>
#include <math.h>

#define LQ_ 5440
#define NB_ 8
#define NQ_ (NB_ * LQ_)   // 43520
#define D_  256
#define NH_ 8
#define HD_ 32

typedef __attribute__((ext_vector_type(8))) short short8;
typedef __attribute__((ext_vector_type(4))) float f32x4;

__device__ __forceinline__ ushort f2bf(float f) {
    union { float f; unsigned u; } v; v.f = f;
    unsigned u = v.u;
    unsigned r = (u + 0x7FFFu + ((u >> 16) & 1u)) >> 16;
    return (ushort)r;
}
__device__ __forceinline__ float bf2f(ushort u) {
    union { unsigned u; float f; } v; v.u = ((unsigned)u) << 16; return v.f;
}

// ---------------------------------------------------------------------------
// Input prep: s_bf = bf16(src), q_bf = bf16(src+pos). 4 elems/thread.
// ---------------------------------------------------------------------------
__global__ void make_bf_inputs(const float* __restrict__ src, const float* __restrict__ pos,
                               ushort* __restrict__ s_bf, ushort* __restrict__ q_bf) {
    const int i = blockIdx.x * blockDim.x + threadIdx.x;
    const float4 s = ((const float4*)src)[i];
    const float4 p = ((const float4*)pos)[i];
    ushort4 a, b;
    a.x = f2bf(s.x); a.y = f2bf(s.y); a.z = f2bf(s.z); a.w = f2bf(s.w);
    b.x = f2bf(s.x + p.x); b.y = f2bf(s.y + p.y); b.z = f2bf(s.z + p.z); b.w = f2bf(s.w + p.w);
    ((ushort4*)s_bf)[i] = a;
    ((ushort4*)q_bf)[i] = b;
}

// ---------------------------------------------------------------------------
// Weight transpose + bf16 cast: W [K,N] fp32 -> Wt [N,K] bf16.
// ---------------------------------------------------------------------------
__global__ void transpose_w(const float* __restrict__ W, ushort* __restrict__ Wt, int K, int N) {
    __shared__ float tile[32][33];
    const int bx = blockIdx.x;   // n tile
    const int by = blockIdx.y;   // k tile
    const int tx = threadIdx.x;  // 0..31
    const int ty = threadIdx.y;  // 0..7
    for (int i = ty; i < 32; i += 8)
        tile[i][tx] = W[(size_t)(by * 32 + i) * N + bx * 32 + tx];
    __syncthreads();
    for (int i = ty; i < 32; i += 8)
        Wt[(size_t)(bx * 32 + i) * K + by * 32 + tx] = f2bf(tile[tx][i]);
}

// ---------------------------------------------------------------------------
// MFMA GEMM: C[M,N] = A[M,K](bf16) @ Bt[N,K](bf16)^T + bias, opt ReLU.
// 128x128 tile, BK=64, 4 waves, 4x4 16x16x32 tiles/wave. fp32 or bf16 out.
// ---------------------------------------------------------------------------
#define BM 128
#define BN 128
#define BKE 64
#define LDE 72   // padded LDS row (elems): 144 B -> 2-way banked (free)

__global__ __launch_bounds__(256)
void mfma_gemm(const ushort* __restrict__ A, const ushort* __restrict__ Bt,
               const float* __restrict__ bias, float* __restrict__ Cf,
               ushort* __restrict__ Cb, int N, int K, int relu) {
    __shared__ ushort lA[BM * LDE];
    __shared__ ushort lB[BN * LDE];
    const int t    = threadIdx.x;
    const int row0 = blockIdx.x * BM;
    const int col0 = blockIdx.y * BN;
    const int w    = t >> 6;
    const int lane = t & 63;
    const int lr   = lane & 15;
    const int quad = lane >> 4;
    const int wm   = (w >> 1) * 64;
    const int wn   = (w & 1) * 64;

    f32x4 acc[4][4];
    #pragma unroll
    for (int i = 0; i < 4; ++i)
        #pragma unroll
        for (int j = 0; j < 4; ++j)
            acc[i][j] = (f32x4){0.f, 0.f, 0.f, 0.f};

    const int sr = t >> 3;        // 0..31
    const int sc = (t & 7) * 8;   // elem offset in row

    for (int k0 = 0; k0 < K; k0 += BKE) {
        __syncthreads();
        #pragma unroll
        for (int g = 0; g < 4; ++g) {
            const int r = sr + g * 32;
            *(short8*)(lA + r * LDE + sc) = *(const short8*)(A  + (size_t)(row0 + r) * K + k0 + sc);
            *(short8*)(lB + r * LDE + sc) = *(const short8*)(Bt + (size_t)(col0 + r) * K + k0 + sc);
        }
        __syncthreads();
        #pragma unroll
        for (int kk = 0; kk < 2; ++kk) {
            short8 af[4], bfr[4];
            #pragma unroll
            for (int i = 0; i < 4; ++i)
                af[i] = *(const short8*)(lA + (wm + i * 16 + lr) * LDE + kk * 32 + quad * 8);
            #pragma unroll
            for (int j = 0; j < 4; ++j)
                bfr[j] = *(const short8*)(lB + (wn + j * 16 + lr) * LDE + kk * 32 + quad * 8);
            #pragma unroll
            for (int i = 0; i < 4; ++i)
                #pragma unroll
                for (int j = 0; j < 4; ++j)
                    acc[i][j] = __builtin_amdgcn_mfma_f32_16x16x32_bf16(af[i], bfr[j], acc[i][j], 0, 0, 0);
        }
    }

    #pragma unroll
    for (int j = 0; j < 4; ++j) {
        const int col = col0 + wn + j * 16 + lr;
        const float bb = bias ? bias[col] : 0.f;
        #pragma unroll
        for (int i = 0; i < 4; ++i) {
            const int rbase = row0 + wm + i * 16 + quad * 4;
            #pragma unroll
            for (int r = 0; r < 4; ++r) {
                float v = acc[i][j][r] + bb;
                if (relu) v = fmaxf(v, 0.f);
                if (Cf) Cf[(size_t)(rbase + r) * N + col] = v;
                else    Cb[(size_t)(rbase + r) * N + col] = f2bf(v);
            }
        }
    }
}

// ---------------------------------------------------------------------------
// Fused softmax + deformable bilinear sampling.
// Block = 256 threads, 2 queries/block.
// Phase 1: thread u = (h,p) per query: softmax over the 16 points (shfl
//          butterfly), compute 4 clamped corner offsets + 4 folded weights
//          -> LDS.
// Phase 2: thread u = (h,d2) per query: 16 points x 4 unconditional uint
//          loads (2 bf16 each), weights broadcast from LDS.
// value bf16 (N,Lq,NH,HD); logits fp32 (N,Lq,NH,16); off fp32 (N,Lq,NH,16,2);
// refp (N,Lq,NL,2); out bf16 (N,Lq,NH,HD).
// ---------------------------------------------------------------------------
__global__ __launch_bounds__(256)
void msda_sample(const ushort* __restrict__ value, const float* __restrict__ off,
                 const float* __restrict__ logits, const float* __restrict__ refp,
                 ushort* __restrict__ out) {
    __shared__ int   s_addr[256][4];
    __shared__ float s_w[256][4];

    const int t  = threadIdx.x;
    const int tq = t >> 7;          // 0..1
    const int u  = t & 127;
    const int nq = blockIdx.x * 2 + tq;
    const int n  = nq / LQ_;

    // ---------------- phase 1: (h,p) ----------------
    {
        const int h = u >> 4;
        const int p = u & 15;
        const int l = p >> 2;

        const int starts[4] = {0, 4096, 5120, 5376};
        const int dims[4]   = {64, 32, 16, 8};
        const int Wl = dims[l];

        // softmax over 16 points (lanes with same (tq,h), p = low 4 lane bits)
        float a = logits[(size_t)nq * 128 + u];
        float m = a;
        #pragma unroll
        for (int o = 8; o > 0; o >>= 1) m = fmaxf(m, __shfl_xor(m, o));
        float e = __expf(a - m);
        float s = e;
        #pragma unroll
        for (int o = 8; o > 0; o >>= 1) s += __shfl_xor(s, o);
        const float wgt = e / s;

        const float rx = refp[(size_t)nq * 8 + l * 2 + 0];
        const float ry = refp[(size_t)nq * 8 + l * 2 + 1];
        const float ox = off[(size_t)nq * 256 + u * 2 + 0];
        const float oy = off[(size_t)nq * 256 + u * 2 + 1];

        const float fw = (float)Wl;
        const float x  = (rx + ox / fw) * fw - 0.5f;
        const float y  = (ry + oy / fw) * fw - 0.5f;
        const float x0f = floorf(x), y0f = floorf(y);
        const int   x0 = (int)x0f, y0 = (int)y0f;
        const float wx1 = x - x0f, wy1 = y - y0f;
        const float wx0 = 1.f - wx1, wy0 = 1.f - wy1;

        const float xm0 = (x0 >= 0 && x0 < Wl) ? 1.f : 0.f;
        const float xm1 = (x0 + 1 >= 0 && x0 + 1 < Wl) ? 1.f : 0.f;
        const float ym0 = (y0 >= 0 && y0 < Wl) ? 1.f : 0.f;
        const float ym1 = (y0 + 1 >= 0 && y0 + 1 < Wl) ? 1.f : 0.f;

        const int x0c = min(max(x0, 0), Wl - 1);
        const int x1c = min(max(x0 + 1, 0), Wl - 1);
        const int y0c = min(max(y0, 0), Wl - 1);
        const int y1c = min(max(y0 + 1, 0), Wl - 1);

        const int base = (n * LQ_ + starts[l]) * 256 + h * 32;
        s_addr[t][0] = base + (y0c * Wl + x0c) * 256;
        s_addr[t][1] = base + (y0c * Wl + x1c) * 256;
        s_addr[t][2] = base + (y1c * Wl + x0c) * 256;
        s_addr[t][3] = base + (y1c * Wl + x1c) * 256;
        s_w[t][0] = wgt * wy0 * wx0 * ym0 * xm0;
        s_w[t][1] = wgt * wy0 * wx1 * ym0 * xm1;
        s_w[t][2] = wgt * wy1 * wx0 * ym1 * xm0;
        s_w[t][3] = wgt * wy1 * wx1 * ym1 * xm1;
    }
    __syncthreads();

    // ---------------- phase 2: (h,d2) ----------------
    {
        const int h   = u >> 4;
        const int d2  = u & 15;       // uint index: d = 2*d2, 2*d2+1
        const int sb  = tq * 128 + h * 16;
        const uint doff = 2 * d2;

        float acc0 = 0.f, acc1 = 0.f;
        #pragma unroll 4
        for (int p = 0; p < 16; ++p) {
            const int*   ap = s_addr[sb + p];
            const float* wp = s_w[sb + p];
            #pragma unroll
            for (int c = 0; c < 4; ++c) {
                const uint v = *(const uint*)(value + ap[c] + doff);
                const float w = wp[c];
                acc0 += w * bf2f((ushort)(v & 0xffffu));
                acc1 += w * bf2f((ushort)(v >> 16));
            }
        }
        const uint packed = (uint)f2bf(acc0) | ((uint)f2bf(acc1) << 16);
        ((uint*)out)[(size_t)nq * 128 + u] = packed;
    }
}

// ---------------------------------------------------------------------------
// x = LayerNorm(a + b); writes fp32 x and optionally bf16 x.
// ---------------------------------------------------------------------------
__global__ void add_ln(const float* __restrict__ a, const float* __restrict__ b,
                       const float* __restrict__ g, const float* __restrict__ be,
                       float* __restrict__ xf, ushort* __restrict__ xb) {
    const int row = blockIdx.x;
    const int t   = threadIdx.x;
    const size_t idx = (size_t)row * 256 + t;
    const float x = a[idx] + b[idx];

    __shared__ float sm[4];
    float v = x;
    #pragma unroll
    for (int o = 32; o > 0; o >>= 1) v += __shfl_down(v, o);
    if ((t & 63) == 0) sm[t >> 6] = v;
    __syncthreads();
    const float mu = (sm[0] + sm[1] + sm[2] + sm[3]) * (1.f / 256.f);
    __syncthreads();

    const float dx = x - mu;
    v = dx * dx;
    #pragma unroll
    for (int o = 32; o > 0; o >>= 1) v += __shfl_down(v, o);
    if ((t & 63) == 0) sm[t >> 6] = v;
    __syncthreads();
    const float var = (sm[0] + sm[1] + sm[2] + sm[3]) * (1.f / 256.f);

    const float y = dx * rsqrtf(var + 1e-5f) * g[t] + be[t];
    xf[idx] = y;
    if (xb) xb[idx] = f2bf(y);
}

// ---------------------------------------------------------------------------
extern "C" void kernel_launch(void* const* d_in, const int* in_sizes, int n_in,
                              void* d_out, int out_size, void* d_ws, size_t ws_size,
                              hipStream_t stream) {
    const float* src     = (const float*)d_in[0];
    const float* pos     = (const float*)d_in[1];
    const float* refp    = (const float*)d_in[2];
    const float* W_value = (const float*)d_in[4];
    const float* b_value = (const float*)d_in[5];
    const float* W_off   = (const float*)d_in[6];
    const float* b_off   = (const float*)d_in[7];
    const float* W_attn  = (const float*)d_in[8];
    const float* b_attn  = (const float*)d_in[9];
    const float* W_out   = (const float*)d_in[10];
    const float* b_out   = (const float*)d_in[11];
    const float* ln1g    = (const float*)d_in[12];
    const float* ln1b    = (const float*)d_in[13];
    const float* W1      = (const float*)d_in[14];
    const float* b1      = (const float*)d_in[15];
    const float* W2      = (const float*)d_in[16];
    const float* b2      = (const float*)d_in[17];
    const float* ln2g    = (const float*)d_in[18];
    const float* ln2b    = (const float*)d_in[19];
    float* out = (float*)d_out;
    char*  ws  = (char*)d_ws;

    // ---- workspace layout (byte offsets) ----
    const size_t SZ_BF = (size_t)NQ_ * 256 * 2;   // 22,282,240
    const size_t SZ_F  = (size_t)NQ_ * 256 * 4;   // 44,564,480
    ushort* s_bf    = (ushort*)(ws);                            // [0, 22.28M)
    ushort* q_bf    = (ushort*)(ws + SZ_BF);                    // [22.28M, 44.56M)
    ushort* val_bf  = (ushort*)(ws + 2 * SZ_BF);                // [44.56M, 66.85M)
    float*  offb    = (float*) (ws + 3 * SZ_BF);                // [66.85M, 111.41M)
    float*  attnb   = (float*) (ws + 3 * SZ_BF + SZ_F);         // [111.41M, 133.69M)  logits
    ushort* samp_bf = (ushort*)(ws + 4 * SZ_BF + SZ_F);         // [133.69M, 155.98M)
    ushort* h_bf    = (ushort*)(ws);                            // overlays [0, 89.13M) — s/q/val/off all dead
    ushort* x_bf    = (ushort*)(ws + 3 * SZ_BF + SZ_F);         // overlays attnb (dead after sampling)
    char*   wbase   = ws + 5 * SZ_BF + SZ_F;                    // 155.98M
    ushort* Wv_t    = (ushort*)(wbase);
    ushort* Woff_t  = (ushort*)(wbase + 131072);
    ushort* Wattn_t = (ushort*)(wbase + 262144);
    ushort* Wout_t  = (ushort*)(wbase + 327680);
    ushort* W1_t    = (ushort*)(wbase + 458752);
    ushort* W2_t    = (ushort*)(wbase + 983040);
    char*   fbase   = wbase + 1507328;
    float*  src2    = (float*)(fbase);                          // also ffn2
    float*  xf      = (float*)(fbase + SZ_F);

    // 0. bf16 inputs
    make_bf_inputs<<<dim3((NQ_ * 256 / 4) / 256), 256, 0, stream>>>(src, pos, s_bf, q_bf);
    // 0b. weight transposes (fp32 [K,N] -> bf16 [N,K])
    transpose_w<<<dim3(8, 8),  dim3(32, 8), 0, stream>>>(W_value, Wv_t,   256, 256);
    transpose_w<<<dim3(8, 8),  dim3(32, 8), 0, stream>>>(W_off,   Woff_t, 256, 256);
    transpose_w<<<dim3(4, 8),  dim3(32, 8), 0, stream>>>(W_attn,  Wattn_t,256, 128);
    transpose_w<<<dim3(8, 8),  dim3(32, 8), 0, stream>>>(W_out,   Wout_t, 256, 256);
    transpose_w<<<dim3(32, 8), dim3(32, 8), 0, stream>>>(W1,      W1_t,   256, 1024);
    transpose_w<<<dim3(8, 32), dim3(32, 8), 0, stream>>>(W2,      W2_t,   1024, 256);

    const int MT = NQ_ / BM;  // 340

    // 1. value = src @ Wv + bv  (bf16 out)
    mfma_gemm<<<dim3(MT, 2), 256, 0, stream>>>(s_bf, Wv_t, b_value, nullptr, val_bf, 256, 256, 0);
    // 2. off = q @ Woff + boff  (fp32 out)
    mfma_gemm<<<dim3(MT, 2), 256, 0, stream>>>(q_bf, Woff_t, b_off, offb, nullptr, 256, 256, 0);
    // 3. attn logits = q @ Wattn + battn (fp32 out)
    mfma_gemm<<<dim3(MT, 1), 256, 0, stream>>>(q_bf, Wattn_t, b_attn, attnb, nullptr, 128, 256, 0);
    // 4+5. fused softmax + sampling -> bf16
    msda_sample<<<dim3(NQ_ / 2), 256, 0, stream>>>(val_bf, offb, attnb, refp, samp_bf);
    // 6. src2 = sampled @ Wout + bout (fp32)
    mfma_gemm<<<dim3(MT, 2), 256, 0, stream>>>(samp_bf, Wout_t, b_out, src2, nullptr, 256, 256, 0);
    // 7. x = LN(src + src2) -> fp32 + bf16
    add_ln<<<dim3(NQ_), 256, 0, stream>>>(src, src2, ln1g, ln1b, xf, x_bf);
    // 8. h = relu(x @ W1 + b1) -> bf16
    mfma_gemm<<<dim3(MT, 8), 256, 0, stream>>>(x_bf, W1_t, b1, nullptr, h_bf, 1024, 256, 1);
    // 9. ffn2 = h @ W2 + b2 -> fp32 (overlays src2)
    mfma_gemm<<<dim3(MT, 2), 256, 0, stream>>>(h_bf, W2_t, b2, src2, nullptr, 256, 1024, 0);
    // 10. out = LN(x + ffn2)
    add_ln<<<dim3(NQ_), 256, 0, stream>>>(xf, src2, ln2g, ln2b, out, nullptr);
}